// Round 3
// baseline (132.135 us; speedup 1.0000x reference)
//
#include <hip/hip_runtime.h>
#include <hip/hip_bf16.h>
#include <cstdint>

#define NPOS 512
#define NNEG 512
#define BATCH 8
#define DDIM 128
#define NLEM 32768
#define NX_ELEM (BATCH * (NPOS + NNEG) * DDIM)  // 1048576
#define NM_ELEM (NLEM * DDIM)                   // 4194304
#define GRID_GEMM 256
#define NT_TILES 8320  // 32 * 260 (256 sim by + 4 noise by)

typedef __attribute__((ext_vector_type(4))) float f32x4;
typedef __attribute__((ext_vector_type(16))) float f32x16;
typedef __attribute__((ext_vector_type(8))) short short8;

__device__ __forceinline__ unsigned short f2bf(float f) {
  unsigned u = __float_as_uint(f);
  u = (u + 0x7FFFu + ((u >> 16) & 1u)) >> 16;
  return (unsigned short)u;
}

__device__ __forceinline__ short8 cvt8(f32x4 a0, f32x4 a1) {
  short8 w;
  w[0] = (short)f2bf(a0[0]); w[1] = (short)f2bf(a0[1]);
  w[2] = (short)f2bf(a0[2]); w[3] = (short)f2bf(a0[3]);
  w[4] = (short)f2bf(a1[0]); w[5] = (short)f2bf(a1[1]);
  w[6] = (short)f2bf(a1[2]); w[7] = (short)f2bf(a1[3]);
  return w;
}

// async 16B global -> LDS (linear dest: wave-uniform base + lane*16)
__device__ __forceinline__ void async16(const void* g, void* l) {
  __builtin_amdgcn_global_load_lds(
      (const __attribute__((address_space(1))) unsigned int*)g,
      (__attribute__((address_space(3))) unsigned int*)l, 16, 0, 0);
}

// ---- shared newmem row logic (one wave per row, exact f32) ----
__device__ __forceinline__ void newmem_row(int r, int lane, const float* __restrict__ X,
                                           const int* __restrict__ vis,
                                           const float* __restrict__ Mem, int start,
                                           float* __restrict__ out) {
  const int d0 = lane, d1 = lane + 64;
  float v0, v1;
  if (r < NPOS) {
    const float s0 = Mem[(size_t)r * DDIM + d0];
    const float s1 = Mem[(size_t)r * DDIM + d1];
    float a0 = 0.f, a1 = 0.f;
#pragma unroll
    for (int b = 0; b < BATCH; ++b) {
      const float w = (float)vis[b * NPOS + r];
      const float* px = X + (size_t)(b * (NPOS + NNEG) + r) * DDIM;
      a0 += w * px[d0];
      a1 += w * px[d1];
    }
    v0 = 0.5f * s0 + 0.0625f * a0;
    v1 = 0.5f * s1 + 0.0625f * a1;
  } else if (r >= start && r < start + BATCH * NNEG) {
    const int q = r - start;
    const int b = q >> 9, n = q & 511;
    const float* px = X + (size_t)(b * (NPOS + NNEG) + NPOS + n) * DDIM;
    v0 = px[d0];
    v1 = px[d1];
  } else {
    v0 = Mem[(size_t)r * DDIM + d0];
    v1 = Mem[(size_t)r * DDIM + d1];
  }
  float s = v0 * v0 + v1 * v1;
#pragma unroll
  for (int off = 32; off; off >>= 1) s += __shfl_xor(s, off, 64);
  const float inv = 1.0f / fmaxf(sqrtf(s), 1e-12f);
  out[(size_t)r * DDIM + d0] = v0 * inv;
  out[(size_t)r * DDIM + d1] = v1 * inv;
}

// ==== prep: convert x+memory to bf16 in ws, write y_idx, write new_mem ====
__global__ __launch_bounds__(256) void prep_kernel(
    const float* __restrict__ X, const int* __restrict__ y,
    const int* __restrict__ vis, const float* __restrict__ Mem,
    const int* __restrict__ lru_p, unsigned short* __restrict__ xb,
    unsigned short* __restrict__ mb, float* __restrict__ out_y,
    float* __restrict__ out_mem) {
  const int blk = blockIdx.x;
  if (blk < 512) {
    const size_t i = ((size_t)blk * 256 + threadIdx.x) * 8;
    *(short8*)(xb + i) = cvt8(*(const f32x4*)(X + i), *(const f32x4*)(X + i + 4));
  } else if (blk < 2560) {
    const size_t i = ((size_t)(blk - 512) * 256 + threadIdx.x) * 8;
    *(short8*)(mb + i) = cvt8(*(const f32x4*)(Mem + i), *(const f32x4*)(Mem + i + 4));
  } else if (blk < 2576) {
    const int i = (blk - 2560) * 256 + threadIdx.x;
    out_y[i] = (float)y[i];
  } else {
    const int r = (blk - 2576) * 4 + (threadIdx.x >> 6);
    const int start = NPOS + lru_p[0] * (NNEG * BATCH);
    newmem_row(r, threadIdx.x & 63, X, vis, Mem, start, out_mem);
  }
}

// ==== persistent double-buffered GEMM ====
// tile T: bx = T&31 (m0 = bx*128), by = T>>5; by<256 -> sim, else noise.
// Each block owns tiles T = b + k*256 (fixed bx per block -> A tile L2-hot).
__global__ __launch_bounds__(256) void gemm_persist_kernel(
    const unsigned short* __restrict__ Xb, const unsigned short* __restrict__ Mb,
    float* __restrict__ Csim, float* __restrict__ Cnoise) {
  __shared__ short lds[2][2][128 * 128];  // 128 KB: [parity][A|B][tile]

  const int t = threadIdx.x;
  const int lane = t & 63, wv = t >> 6;
  const int rl = lane >> 4, slot = lane & 15;
  const int wr = wv >> 1, wc = wv & 1;
  const int la = lane & 31, lb = lane >> 5;

  const int b = blockIdx.x;
  const int nk = (NT_TILES - b + GRID_GEMM - 1) / GRID_GEMM;

  auto stage = [&](int p, int T) {
    const int m0 = (T & 31) * 128;
    const int by = T >> 5;
    const int n0 = (by < 256 ? by : by - 256) * 128;
    const int a_off = (by < 256) ? 0 : NPOS;
    const int xbase = ((m0 >> 9) << 10) + (m0 & 511) + a_off;
    short* A = lds[p][0];
    short* B = lds[p][1];
#pragma unroll
    for (int i = 0; i < 8; ++i) {
      const int rowb = wv * 32 + i * 4;  // wave-uniform base row
      const int row = rowb + rl;
      const int ss = slot ^ (row & 15);  // inverse-swizzled source (involution)
      async16(Xb + (size_t)(xbase + row) * DDIM + ss * 8, &A[rowb * 128]);
      async16(Mb + (size_t)(n0 + row) * DDIM + ss * 8, &B[rowb * 128]);
    }
  };

  // prologue: fill buffer 0, full drain, barrier
  stage(0, b);
  asm volatile("s_waitcnt vmcnt(0)" ::: "memory");
  __builtin_amdgcn_s_barrier();
  __builtin_amdgcn_sched_barrier(0);

  int p = 0;
  for (int k = 0; k < nk; ++k) {
    const int T = b + k * GRID_GEMM;
    // issue next tile's loads first (so in-flight stores outnumber them)
    if (k + 1 < nk) stage(p ^ 1, T + GRID_GEMM);

    // ---- compute from lds[p] ----
    const short* A = lds[p][0];
    const short* B = lds[p][1];
    f32x16 acc[2][2] = {};
#pragma unroll
    for (int kk = 0; kk < 8; ++kk) {
      short8 af[2], bfr[2];
#pragma unroll
      for (int m2 = 0; m2 < 2; ++m2) {
        const int row = wr * 64 + m2 * 32 + la;
        const int ss = ((kk * 2 + lb) ^ (row & 15)) * 8;
        af[m2] = *(const short8*)&A[row * 128 + ss];
      }
#pragma unroll
      for (int n2 = 0; n2 < 2; ++n2) {
        const int row = wc * 64 + n2 * 32 + la;
        const int ss = ((kk * 2 + lb) ^ (row & 15)) * 8;
        bfr[n2] = *(const short8*)&B[row * 128 + ss];
      }
#pragma unroll
      for (int m2 = 0; m2 < 2; ++m2)
#pragma unroll
        for (int n2 = 0; n2 < 2; ++n2)
          acc[m2][n2] = __builtin_amdgcn_mfma_f32_32x32x16_bf16(
              af[m2], bfr[n2], acc[m2][n2], 0, 0, 0);
    }

    // ---- store tile T ----
    const int m0 = (T & 31) * 128;
    const int by = T >> 5;
    float* C;
    int ldc, n0c;
    if (by < 256) { C = Csim; ldc = NLEM; n0c = by * 128; }
    else          { C = Cnoise; ldc = NPOS; n0c = (by - 256) * 128; }
#pragma unroll
    for (int m2 = 0; m2 < 2; ++m2) {
#pragma unroll
      for (int n2 = 0; n2 < 2; ++n2) {
        const int col = n0c + wc * 64 + n2 * 32 + la;
        const int rbase = m0 + wr * 64 + m2 * 32 + lb * 4;
#pragma unroll
        for (int r = 0; r < 16; ++r) {
          const int row = rbase + (r & 3) + 8 * (r >> 2);
          C[(size_t)row * ldc + col] = acc[m2][n2][r];
        }
      }
    }

    // ---- counted wait: any N<64 guarantees the 16 stage loads (issued before
    // the 64 stores) have retired; leaves ~60 stores draining across barrier.
    if (k + 1 < nk) {
      asm volatile("s_waitcnt vmcnt(60)" ::: "memory");
      __builtin_amdgcn_s_barrier();
      __builtin_amdgcn_sched_barrier(0);
    }
    p ^= 1;
  }
}

// ================= fallback path (used only if ws too small) ====
__global__ __launch_bounds__(256) void gemm_conv_kernel(
    const float* __restrict__ X, const float* __restrict__ Bm,
    float* __restrict__ C, int ldc, int a_off) {
  __shared__ short lds[2 * 128 * 128];
  short* ldsA = lds;
  short* ldsB = lds + 128 * 128;
  const int t = threadIdx.x;
  const int m0 = blockIdx.x * 128;
  const int n0 = blockIdx.y * 128;
  const int slot = t & 15;
  const int rsub = t >> 4;
#pragma unroll
  for (int it = 0; it < 8; ++it) {
    const int row = it * 16 + rsub;
    const int gr = m0 + row;
    const int xrow = ((gr >> 9) << 10) + (gr & 511) + a_off;
    const f32x4* pa = (const f32x4*)(X + (size_t)xrow * DDIM + slot * 8);
    const f32x4* pb = (const f32x4*)(Bm + (size_t)(n0 + row) * DDIM + slot * 8);
    short8 wa = cvt8(pa[0], pa[1]);
    short8 wb = cvt8(pb[0], pb[1]);
    const int ss = (slot ^ (row & 15)) * 8;
    *(short8*)&ldsA[row * 128 + ss] = wa;
    *(short8*)&ldsB[row * 128 + ss] = wb;
  }
  __syncthreads();
  const int lane = t & 63;
  const int wv = t >> 6;
  const int wr = wv >> 1, wc = wv & 1;
  const int la = lane & 31, lb = lane >> 5;
  f32x16 acc[2][2] = {};
#pragma unroll
  for (int kk = 0; kk < 8; ++kk) {
    short8 af[2], bfr[2];
#pragma unroll
    for (int m2 = 0; m2 < 2; ++m2) {
      const int row = wr * 64 + m2 * 32 + la;
      const int ss = ((kk * 2 + lb) ^ (row & 15)) * 8;
      af[m2] = *(const short8*)&ldsA[row * 128 + ss];
    }
#pragma unroll
    for (int n2 = 0; n2 < 2; ++n2) {
      const int row = wc * 64 + n2 * 32 + la;
      const int ss = ((kk * 2 + lb) ^ (row & 15)) * 8;
      bfr[n2] = *(const short8*)&ldsB[row * 128 + ss];
    }
#pragma unroll
    for (int m2 = 0; m2 < 2; ++m2)
#pragma unroll
      for (int n2 = 0; n2 < 2; ++n2)
        acc[m2][n2] = __builtin_amdgcn_mfma_f32_32x32x16_bf16(
            af[m2], bfr[n2], acc[m2][n2], 0, 0, 0);
  }
#pragma unroll
  for (int m2 = 0; m2 < 2; ++m2)
#pragma unroll
    for (int n2 = 0; n2 < 2; ++n2) {
      const int col = n0 + wc * 64 + n2 * 32 + la;
      const int rbase = m0 + wr * 64 + m2 * 32 + lb * 4;
#pragma unroll
      for (int r = 0; r < 16; ++r) {
        const int row = rbase + (r & 3) + 8 * (r >> 2);
        C[(size_t)row * ldc + col] = acc[m2][n2][r];
      }
    }
}

__global__ void y_kernel(const int* __restrict__ y, float* __restrict__ out) {
  const int i = blockIdx.x * blockDim.x + threadIdx.x;
  if (i < BATCH * NPOS) out[i] = (float)y[i];
}

__global__ __launch_bounds__(256) void newmem_kernel(
    const float* __restrict__ X, const int* __restrict__ vis,
    const float* __restrict__ Mem, const int* __restrict__ lru_p,
    float* __restrict__ out) {
  const int r = blockIdx.x * 4 + (threadIdx.x >> 6);
  const int start = NPOS + lru_p[0] * (NNEG * BATCH);
  newmem_row(r, threadIdx.x & 63, X, vis, Mem, start, out);
}

extern "C" void kernel_launch(void* const* d_in, const int* in_sizes, int n_in,
                              void* d_out, int out_size, void* d_ws, size_t ws_size,
                              hipStream_t stream) {
  const float* x = (const float*)d_in[0];
  const int* y = (const int*)d_in[1];
  const int* visible = (const int*)d_in[2];
  const float* memory = (const float*)d_in[3];
  const int* lru = (const int*)d_in[4];
  float* out = (float*)d_out;

  const size_t OFF_Y = (size_t)BATCH * NPOS * NLEM;
  const size_t OFF_NOISE = OFF_Y + (size_t)BATCH * NPOS;
  const size_t OFF_MEM = OFF_NOISE + (size_t)BATCH * NNEG * NPOS;

  const size_t need = (size_t)(NX_ELEM + NM_ELEM) * 2;  // 10.5 MB bf16 scratch
  if (ws_size >= need) {
    unsigned short* xb = (unsigned short*)d_ws;
    unsigned short* mb = xb + NX_ELEM;
    prep_kernel<<<2576 + NLEM / 4, 256, 0, stream>>>(
        x, y, visible, memory, lru, xb, mb, out + OFF_Y, out + OFF_MEM);
    gemm_persist_kernel<<<GRID_GEMM, 256, 0, stream>>>(
        xb, mb, out, out + OFF_NOISE);
  } else {
    gemm_conv_kernel<<<dim3(32, 256), 256, 0, stream>>>(x, memory, out, NLEM, 0);
    gemm_conv_kernel<<<dim3(32, 4), 256, 0, stream>>>(x, memory, out + OFF_NOISE, NPOS, NPOS);
    y_kernel<<<16, 256, 0, stream>>>(y, out + OFF_Y);
    newmem_kernel<<<NLEM / 4, 256, 0, stream>>>(x, visible, memory, lru, out + OFF_MEM);
  }
}

// Round 4
// 125.727 us; speedup vs baseline: 1.0510x; 1.0510x over previous
//
#include <hip/hip_runtime.h>
#include <hip/hip_bf16.h>
#include <cstdint>

#define NPOS 512
#define NNEG 512
#define BATCH 8
#define DDIM 128
#define NLEM 32768
#define NX_ELEM (BATCH * (NPOS + NNEG) * DDIM)  // 1048576
#define NM_ELEM (NLEM * DDIM)                   // 4194304
#define NK_STEPS 32                             // 4096 rows / 128

typedef __attribute__((ext_vector_type(4))) float f32x4;
typedef __attribute__((ext_vector_type(16))) float f32x16;
typedef __attribute__((ext_vector_type(8))) short short8;

__device__ __forceinline__ unsigned short f2bf(float f) {
  unsigned u = __float_as_uint(f);
  u = (u + 0x7FFFu + ((u >> 16) & 1u)) >> 16;
  return (unsigned short)u;
}

__device__ __forceinline__ short8 cvt8(f32x4 a0, f32x4 a1) {
  short8 w;
  w[0] = (short)f2bf(a0[0]); w[1] = (short)f2bf(a0[1]);
  w[2] = (short)f2bf(a0[2]); w[3] = (short)f2bf(a0[3]);
  w[4] = (short)f2bf(a1[0]); w[5] = (short)f2bf(a1[1]);
  w[6] = (short)f2bf(a1[2]); w[7] = (short)f2bf(a1[3]);
  return w;
}

// async 16B global -> LDS (linear dest: wave-uniform base + lane*16)
__device__ __forceinline__ void async16(const void* g, void* l) {
  __builtin_amdgcn_global_load_lds(
      (const __attribute__((address_space(1))) unsigned int*)g,
      (__attribute__((address_space(3))) unsigned int*)l, 16, 0, 0);
}

// ---- shared newmem row logic (one wave per row, exact f32) ----
__device__ __forceinline__ void newmem_row(int r, int lane, const float* __restrict__ X,
                                           const int* __restrict__ vis,
                                           const float* __restrict__ Mem, int start,
                                           float* __restrict__ out) {
  const int d0 = lane, d1 = lane + 64;
  float v0, v1;
  if (r < NPOS) {
    const float s0 = Mem[(size_t)r * DDIM + d0];
    const float s1 = Mem[(size_t)r * DDIM + d1];
    float a0 = 0.f, a1 = 0.f;
#pragma unroll
    for (int b = 0; b < BATCH; ++b) {
      const float w = (float)vis[b * NPOS + r];
      const float* px = X + (size_t)(b * (NPOS + NNEG) + r) * DDIM;
      a0 += w * px[d0];
      a1 += w * px[d1];
    }
    v0 = 0.5f * s0 + 0.0625f * a0;
    v1 = 0.5f * s1 + 0.0625f * a1;
  } else if (r >= start && r < start + BATCH * NNEG) {
    const int q = r - start;
    const int b = q >> 9, n = q & 511;
    const float* px = X + (size_t)(b * (NPOS + NNEG) + NPOS + n) * DDIM;
    v0 = px[d0];
    v1 = px[d1];
  } else {
    v0 = Mem[(size_t)r * DDIM + d0];
    v1 = Mem[(size_t)r * DDIM + d1];
  }
  float s = v0 * v0 + v1 * v1;
#pragma unroll
  for (int off = 32; off; off >>= 1) s += __shfl_xor(s, off, 64);
  const float inv = 1.0f / fmaxf(sqrtf(s), 1e-12f);
  out[(size_t)r * DDIM + d0] = v0 * inv;
  out[(size_t)r * DDIM + d1] = v1 * inv;
}

// ==== prep: bf16 convert (x pos rows + memory), y_idx, new_mem ====
// blocks: [0,256) x-pos-convert | [256,2304) mem-convert | [2304,2320) y | [2320,10512) newmem
__global__ __launch_bounds__(256) void prep_kernel(
    const float* __restrict__ X, const int* __restrict__ y,
    const int* __restrict__ vis, const float* __restrict__ Mem,
    const int* __restrict__ lru_p, unsigned short* __restrict__ xb,
    unsigned short* __restrict__ mb, float* __restrict__ out_y,
    float* __restrict__ out_mem) {
  const int blk = blockIdx.x;
  if (blk < 256) {
    // pos rows only: batch = blk>>5, chunk = blk&31
    const size_t i = (size_t)(blk >> 5) * 131072 + (size_t)(blk & 31) * 2048 +
                     (size_t)threadIdx.x * 8;
    *(short8*)(xb + i) = cvt8(*(const f32x4*)(X + i), *(const f32x4*)(X + i + 4));
  } else if (blk < 2304) {
    const size_t i = ((size_t)(blk - 256) * 256 + threadIdx.x) * 8;
    *(short8*)(mb + i) = cvt8(*(const f32x4*)(Mem + i), *(const f32x4*)(Mem + i + 4));
  } else if (blk < 2320) {
    const int i = (blk - 2304) * 256 + threadIdx.x;
    out_y[i] = (float)y[i];
  } else {
    const int r = (blk - 2320) * 4 + (threadIdx.x >> 6);
    const int start = NPOS + lru_p[0] * (NNEG * BATCH);
    newmem_row(r, threadIdx.x & 63, X, vis, Mem, start, out_mem);
  }
}

// ==== main similarity GEMM: band-persistent, temporally-coherent writes ====
// Block b owns column band n0 = b*128 (B resident in LDS + regs).
// Step k: all blocks compute/write rows [128k, 128k+128) -> contiguous 16MB
// device-wide write band per step (LLC evicts whole rows).
__global__ __launch_bounds__(256, 1) void gemm_band_kernel(
    const unsigned short* __restrict__ Xb, const unsigned short* __restrict__ Mb,
    float* __restrict__ Csim) {
  __shared__ short ldsA[2][128 * 128];  // 64 KB A double-buffer
  __shared__ short ldsB[128 * 128];     // 32 KB resident B band

  const int t = threadIdx.x;
  const int lane = t & 63, wv = t >> 6;
  const int rl = lane >> 4, slot = lane & 15;
  const int wr = wv >> 1, wc = wv & 1;
  const int la = lane & 31, lb = lane >> 5;
  const int b = blockIdx.x;
  const int n0 = b * 128;

  auto stageA = [&](int p, int k) {
    const int m0 = k * 128;
    const int xbase = ((m0 >> 9) << 10) + (m0 & 511);  // pos rows
#pragma unroll
    for (int i = 0; i < 8; ++i) {
      const int rowb = wv * 32 + i * 4;  // wave-uniform base row
      const int row = rowb + rl;
      const int ss = slot ^ (row & 15);  // inverse-swizzled source (involution)
      async16(Xb + (size_t)(xbase + row) * DDIM + ss * 8, &ldsA[p][rowb * 128]);
    }
  };

  // ---- prologue: stage B (once) + A(k=0) ----
#pragma unroll
  for (int i = 0; i < 8; ++i) {
    const int rowb = wv * 32 + i * 4;
    const int row = rowb + rl;
    const int ss = slot ^ (row & 15);
    async16(Mb + (size_t)(n0 + row) * DDIM + ss * 8, &ldsB[rowb * 128]);
  }
  stageA(0, 0);
  asm volatile("s_waitcnt vmcnt(0)" ::: "memory");
  __builtin_amdgcn_s_barrier();
  __builtin_amdgcn_sched_barrier(0);

  // ---- hoist B fragments to registers (64 VGPR) ----
  short8 bfr[8][2];
#pragma unroll
  for (int kk = 0; kk < 8; ++kk)
#pragma unroll
    for (int n2 = 0; n2 < 2; ++n2) {
      const int row = wc * 64 + n2 * 32 + la;
      const int ss = ((kk * 2 + lb) ^ (row & 15)) * 8;
      bfr[kk][n2] = *(const short8*)&ldsB[row * 128 + ss];
    }

  int p = 0;
  for (int k = 0; k < NK_STEPS; ++k) {
    // issue next row-panel's A loads (before stores -> counted wait is valid)
    if (k + 1 < NK_STEPS) stageA(p ^ 1, k + 1);

    f32x16 acc[2][2] = {};
#pragma unroll
    for (int kk = 0; kk < 8; ++kk) {
      short8 af[2];
#pragma unroll
      for (int m2 = 0; m2 < 2; ++m2) {
        const int row = wr * 64 + m2 * 32 + la;
        const int ss = ((kk * 2 + lb) ^ (row & 15)) * 8;
        af[m2] = *(const short8*)&ldsA[p][row * 128 + ss];
      }
#pragma unroll
      for (int m2 = 0; m2 < 2; ++m2)
#pragma unroll
        for (int n2 = 0; n2 < 2; ++n2)
          acc[m2][n2] = __builtin_amdgcn_mfma_f32_32x32x16_bf16(
              af[m2], bfr[kk][n2], acc[m2][n2], 0, 0, 0);
    }

    // ---- store row-panel k of this band ----
    const int m0 = k * 128;
#pragma unroll
    for (int m2 = 0; m2 < 2; ++m2) {
#pragma unroll
      for (int n2 = 0; n2 < 2; ++n2) {
        const int col = n0 + wc * 64 + n2 * 32 + la;
        const int rbase = m0 + wr * 64 + m2 * 32 + lb * 4;
#pragma unroll
        for (int r = 0; r < 16; ++r) {
          const int row = rbase + (r & 3) + 8 * (r >> 2);
          Csim[(size_t)row * NLEM + col] = acc[m2][n2][r];
        }
      }
    }

    // counted wait: 64 stores issued after the 8 A-loads -> vmcnt(60)
    // guarantees loads retired; ~60 stores keep draining across the barrier.
    if (k + 1 < NK_STEPS) {
      asm volatile("s_waitcnt vmcnt(60)" ::: "memory");
      __builtin_amdgcn_s_barrier();
      __builtin_amdgcn_sched_barrier(0);
    }
    p ^= 1;
  }
}

// ==== one-shot convert-GEMM (noise output; also the fallback main GEMM) ====
__global__ __launch_bounds__(256) void gemm_conv_kernel(
    const float* __restrict__ X, const float* __restrict__ Bm,
    float* __restrict__ C, int ldc, int a_off) {
  __shared__ short lds[2 * 128 * 128];
  short* ldsA = lds;
  short* ldsB = lds + 128 * 128;
  const int t = threadIdx.x;
  const int m0 = blockIdx.x * 128;
  const int n0 = blockIdx.y * 128;
  const int slot = t & 15;
  const int rsub = t >> 4;
#pragma unroll
  for (int it = 0; it < 8; ++it) {
    const int row = it * 16 + rsub;
    const int gr = m0 + row;
    const int xrow = ((gr >> 9) << 10) + (gr & 511) + a_off;
    const f32x4* pa = (const f32x4*)(X + (size_t)xrow * DDIM + slot * 8);
    const f32x4* pb = (const f32x4*)(Bm + (size_t)(n0 + row) * DDIM + slot * 8);
    short8 wa = cvt8(pa[0], pa[1]);
    short8 wb = cvt8(pb[0], pb[1]);
    const int ss = (slot ^ (row & 15)) * 8;
    *(short8*)&ldsA[row * 128 + ss] = wa;
    *(short8*)&ldsB[row * 128 + ss] = wb;
  }
  __syncthreads();
  const int lane = t & 63;
  const int wv = t >> 6;
  const int wr = wv >> 1, wc = wv & 1;
  const int la = lane & 31, lb = lane >> 5;
  f32x16 acc[2][2] = {};
#pragma unroll
  for (int kk = 0; kk < 8; ++kk) {
    short8 af[2], bfr[2];
#pragma unroll
    for (int m2 = 0; m2 < 2; ++m2) {
      const int row = wr * 64 + m2 * 32 + la;
      const int ss = ((kk * 2 + lb) ^ (row & 15)) * 8;
      af[m2] = *(const short8*)&ldsA[row * 128 + ss];
    }
#pragma unroll
    for (int n2 = 0; n2 < 2; ++n2) {
      const int row = wc * 64 + n2 * 32 + la;
      const int ss = ((kk * 2 + lb) ^ (row & 15)) * 8;
      bfr[n2] = *(const short8*)&ldsB[row * 128 + ss];
    }
#pragma unroll
    for (int m2 = 0; m2 < 2; ++m2)
#pragma unroll
      for (int n2 = 0; n2 < 2; ++n2)
        acc[m2][n2] = __builtin_amdgcn_mfma_f32_32x32x16_bf16(
            af[m2], bfr[n2], acc[m2][n2], 0, 0, 0);
  }
#pragma unroll
  for (int m2 = 0; m2 < 2; ++m2)
#pragma unroll
    for (int n2 = 0; n2 < 2; ++n2) {
      const int col = n0 + wc * 64 + n2 * 32 + la;
      const int rbase = m0 + wr * 64 + m2 * 32 + lb * 4;
#pragma unroll
      for (int r = 0; r < 16; ++r) {
        const int row = rbase + (r & 3) + 8 * (r >> 2);
        C[(size_t)row * ldc + col] = acc[m2][n2][r];
      }
    }
}

__global__ void y_kernel(const int* __restrict__ y, float* __restrict__ out) {
  const int i = blockIdx.x * blockDim.x + threadIdx.x;
  if (i < BATCH * NPOS) out[i] = (float)y[i];
}

__global__ __launch_bounds__(256) void newmem_kernel(
    const float* __restrict__ X, const int* __restrict__ vis,
    const float* __restrict__ Mem, const int* __restrict__ lru_p,
    float* __restrict__ out) {
  const int r = blockIdx.x * 4 + (threadIdx.x >> 6);
  const int start = NPOS + lru_p[0] * (NNEG * BATCH);
  newmem_row(r, threadIdx.x & 63, X, vis, Mem, start, out);
}

extern "C" void kernel_launch(void* const* d_in, const int* in_sizes, int n_in,
                              void* d_out, int out_size, void* d_ws, size_t ws_size,
                              hipStream_t stream) {
  const float* x = (const float*)d_in[0];
  const int* y = (const int*)d_in[1];
  const int* visible = (const int*)d_in[2];
  const float* memory = (const float*)d_in[3];
  const int* lru = (const int*)d_in[4];
  float* out = (float*)d_out;

  const size_t OFF_Y = (size_t)BATCH * NPOS * NLEM;
  const size_t OFF_NOISE = OFF_Y + (size_t)BATCH * NPOS;
  const size_t OFF_MEM = OFF_NOISE + (size_t)BATCH * NNEG * NPOS;

  const size_t need = (size_t)(NX_ELEM + NM_ELEM) * 2;  // 10.5 MB bf16 scratch
  if (ws_size >= need) {
    unsigned short* xb = (unsigned short*)d_ws;
    unsigned short* mb = xb + NX_ELEM;
    // noise (small, independent of prep): direct f32->bf16 convert GEMM
    gemm_conv_kernel<<<dim3(32, 4), 256, 0, stream>>>(x, memory, out + OFF_NOISE, NPOS, NPOS);
    prep_kernel<<<10512, 256, 0, stream>>>(
        x, y, visible, memory, lru, xb, mb, out + OFF_Y, out + OFF_MEM);
    gemm_band_kernel<<<256, 256, 0, stream>>>(xb, mb, out);
  } else {
    gemm_conv_kernel<<<dim3(32, 256), 256, 0, stream>>>(x, memory, out, NLEM, 0);
    gemm_conv_kernel<<<dim3(32, 4), 256, 0, stream>>>(x, memory, out + OFF_NOISE, NPOS, NPOS);
    y_kernel<<<16, 256, 0, stream>>>(y, out + OFF_Y);
    newmem_kernel<<<NLEM / 4, 256, 0, stream>>>(x, visible, memory, lru, out + OFF_MEM);
  }
}